// Round 7
// baseline (333.762 us; speedup 1.0000x reference)
//
#include <hip/hip_runtime.h>
#include <math.h>
#include <cstddef>

#define BB 4
#define LL 4096
#define DD 256
#define NST 8
#define RANK 16
#define HID 128
#define BL (BB*LL)          // 16384
#define BLD ((size_t)BL*DD) // 4194304
#define CH 128              // scan chunks
#define CLEN 32             // steps per chunk (CH*CLEN == LL)

typedef __bf16 bf16x8 __attribute__((ext_vector_type(8)));
typedef float  f32x4  __attribute__((ext_vector_type(4)));

__device__ __forceinline__ float siluf(float x){ return x / (1.f + __expf(-x)); }
__device__ __forceinline__ float softplus_fast(float x){
  float r = __logf(1.f + __expf(x));
  return x > 15.f ? x : r;
}
// fp32 -> bf16 bits, round-to-nearest-even
__device__ __forceinline__ unsigned short f2bf(float x){
  union { float f; unsigned u; } v; v.f = x;
  unsigned r = v.u + 0x7fffu + ((v.u >> 16) & 1u);
  return (unsigned short)(r >> 16);
}
__device__ __forceinline__ float bf2f(unsigned short u){
  union { unsigned u32; float f; } c; c.u32 = ((unsigned)u) << 16;
  return c.f;
}

// ---------------- RMSNorm: h0 -> bf16, h1 -> fp32 --------------------------------
__global__ __launch_bounds__(64) void rms_kernel(
    const float* __restrict__ x0, const float* __restrict__ w0, unsigned short* __restrict__ o0b,
    const float* __restrict__ x1, const float* __restrict__ w1, float* __restrict__ o1)
{
  const float* x; const float* w;
  if (blockIdx.y == 0){ x = x0; w = w0; } else { x = x1; w = w1; }
  size_t tok = blockIdx.x;
  int lane = threadIdx.x;
  float4 v = ((const float4*)(x + tok*DD))[lane];
  float s = v.x*v.x + v.y*v.y + v.z*v.z + v.w*v.w;
  #pragma unroll
  for (int m = 1; m < 64; m <<= 1) s += __shfl_xor(s, m, 64);
  float scale = 1.f / (sqrtf(s) * (1.f/16.f) + 1e-6f);
  float4 wv = ((const float4*)w)[lane];
  float4 r;
  r.x = v.x*scale*wv.x; r.y = v.y*scale*wv.y; r.z = v.z*scale*wv.z; r.w = v.w*scale*wv.w;
  if (blockIdx.y == 0){
    ushort4 o; o.x=f2bf(r.x); o.y=f2bf(r.y); o.z=f2bf(r.z); o.w=f2bf(r.w);
    ((ushort4*)(o0b + tok*DD))[lane] = o;
  } else {
    ((float4*)(o1 + tok*DD))[lane] = r;
  }
}

// ---------------- weight fp32->bf16 conversion -----------------------------------
__global__ __launch_bounds__(256) void cvt1_kernel(
    const float* __restrict__ s, unsigned short* __restrict__ d, int n)
{
  int i = blockIdx.x*256 + threadIdx.x;
  if (i < n) d[i] = f2bf(s[i]);
}
__global__ __launch_bounds__(256) void cvt3_kernel(
    const float* __restrict__ s0, const float* __restrict__ s1,
    const float* __restrict__ s2, unsigned short* __restrict__ d)
{
  int i = blockIdx.x*256 + threadIdx.x;   // 0..131071
  float v;
  if (i < 65536)       v = s0[i];
  else if (i < 98304)  v = s1[i - 65536];
  else                 v = s2[i - 98304];
  d[i] = f2bf(v);
}

// ---------------- bf16 MFMA GEMM, 64x64 tile: C = A @ Bw^T (+ epilogue) ----------
// EPI: 0 = C=acc ; 1 = C=acc+Add & Cb=bf16(C) ; 2 = C=acc+Add ; 3 = Cb=bf16(acc)
template<int EPI>
__global__ __launch_bounds__(256) void gemm_mfma(
    const unsigned short* __restrict__ A, const unsigned short* __restrict__ Bw,
    float* __restrict__ C, const float* __restrict__ Add,
    unsigned short* __restrict__ Cb, int M, int N, int K)
{
  constexpr int BK = 32, PAD = 8;
  __shared__ __align__(16) unsigned short As[64][BK+PAD];
  __shared__ __align__(16) unsigned short Bs[64][BK+PAD];
  int tid  = threadIdx.x;
  int row0 = blockIdx.x * 64;
  int col0 = blockIdx.y * 64;
  int wave = tid >> 6, lane = tid & 63;
  int wm = (wave >> 1) * 32, wn = (wave & 1) * 32;
  int lm = lane & 15, kq = lane >> 4;
  int sr = tid >> 2, sc8 = (tid & 3) * 8;

  f32x4 acc[2][2];
  #pragma unroll
  for (int i = 0; i < 2; i++)
    #pragma unroll
    for (int j = 0; j < 2; j++) acc[i][j] = (f32x4){0.f,0.f,0.f,0.f};

  for (int k0 = 0; k0 < K; k0 += BK){
    *(int4*)&As[sr][sc8] = *(const int4*)&A [(size_t)(row0 + sr)*K + k0 + sc8];
    *(int4*)&Bs[sr][sc8] = *(const int4*)&Bw[(size_t)(col0 + sr)*K + k0 + sc8];
    __syncthreads();
    bf16x8 af[2], bfv[2];
    #pragma unroll
    for (int i = 0; i < 2; i++) af[i]  = *(const bf16x8*)&As[wm + i*16 + lm][kq*8];
    #pragma unroll
    for (int j = 0; j < 2; j++) bfv[j] = *(const bf16x8*)&Bs[wn + j*16 + lm][kq*8];
    #pragma unroll
    for (int i = 0; i < 2; i++)
      #pragma unroll
      for (int j = 0; j < 2; j++)
        acc[i][j] = __builtin_amdgcn_mfma_f32_16x16x32_bf16(af[i], bfv[j], acc[i][j], 0, 0, 0);
    __syncthreads();
  }

  // C/D layout: col = lane&15, row = (lane>>4)*4 + reg   [m89-verified]
  #pragma unroll
  for (int i = 0; i < 2; i++){
    int rbase = row0 + wm + i*16 + kq*4;
    #pragma unroll
    for (int j = 0; j < 2; j++){
      int col = col0 + wn + j*16 + lm;
      #pragma unroll
      for (int r = 0; r < 4; r++){
        size_t idx = (size_t)(rbase + r)*N + col;
        float v = acc[i][j][r];
        if constexpr (EPI == 1 || EPI == 2) v += Add[idx];
        if constexpr (EPI != 3) C[idx] = v;
        if constexpr (EPI == 1 || EPI == 3) Cb[idx] = f2bf(v);
      }
    }
  }
}

// ---------------- fp32 GEMM (xproj only) -----------------------------------------
template<int BM, int BN, int BK, int TM, int TN>
__global__ __launch_bounds__(256) void gemm_abt(
    const float* __restrict__ A, const float* __restrict__ Bw,
    float* __restrict__ C, int M, int N, int K, int lda, int flipA)
{
  __shared__ __align__(16) float As[BK][BM+4];
  __shared__ __align__(16) float Bs[BK][BN+4];
  int tid = threadIdx.x;
  int row0 = blockIdx.x * BM;
  int col0 = blockIdx.y * BN;
  int tr = tid / (BN/TN);
  int tc = tid % (BN/TN);
  float acc[TM][TN];
  #pragma unroll
  for (int i = 0; i < TM; i++)
    #pragma unroll
    for (int j = 0; j < TN; j++) acc[i][j] = 0.f;

  for (int k0 = 0; k0 < K; k0 += BK){
    #pragma unroll
    for (int e = tid; e < BM*BK; e += 256){
      int r = e / BK, c = e % BK;
      int pr = row0 + r;
      if (flipA){ int b = pr / LL; int t = pr % LL; pr = b*LL + (LL-1-t); }
      As[c][r] = A[(size_t)pr*lda + k0 + c];
    }
    #pragma unroll
    for (int e = tid; e < BN*BK; e += 256){
      int r = e / BK, c = e % BK;
      Bs[c][r] = Bw[(size_t)(col0 + r)*K + k0 + c];
    }
    __syncthreads();
    #pragma unroll
    for (int kk = 0; kk < BK; kk++){
      float a[TM], bfv[TN];
      #pragma unroll
      for (int i = 0; i < TM; i++) a[i] = As[kk][tr*TM + i];
      #pragma unroll
      for (int j = 0; j < TN; j++) bfv[j] = Bs[kk][tc*TN + j];
      #pragma unroll
      for (int i = 0; i < TM; i++)
        #pragma unroll
        for (int j = 0; j < TN; j++) acc[i][j] = fmaf(a[i], bfv[j], acc[i][j]);
    }
    __syncthreads();
  }

  #pragma unroll
  for (int i = 0; i < TM; i++){
    int r = row0 + tr*TM + i;
    size_t base = (size_t)r*N + col0 + tc*TN;
    #pragma unroll
    for (int j = 0; j < TN; j++) C[base + j] = acc[i][j];
  }
}

// =================== Fused front: conv+silu+delta (both dirs) + local scan =======
// Block = (forward chunk cf, b). Owns source tokens [s0-3, s0+CLEN+3).
// Produces forward chunk cf AND backward chunk CH-1-cf via the mirror identity:
// backward output t' = LL-1-(s-3) taps sources s-3..s with reversed weights.
// Writes packed (xc,de) to xde for p3 and runs both local scans -> P, Hout.
__global__ __launch_bounds__(256) void front_kernel(
    const unsigned short* __restrict__ xin,
    const float* __restrict__ xdf, const float* __restrict__ xdb,
    const float* __restrict__ cwf, const float* __restrict__ cbf,
    const float* __restrict__ cwb, const float* __restrict__ cbb,
    const float* __restrict__ dtwf, const float* __restrict__ dtbf,
    const float* __restrict__ dtwb, const float* __restrict__ dtbb,
    const float* __restrict__ Alogf, const float* __restrict__ Alogb,
    unsigned int* __restrict__ xde,
    float* __restrict__ P, float* __restrict__ Hout)
{
  int cf = blockIdx.x;            // forward chunk id
  int b  = blockIdx.y;
  int s0 = cf * CLEN;
  int tb0 = LL - CLEN - s0;       // backward chunk start (chunk id CH-1-cf)
  int d  = threadIdx.x;

  __shared__ float sdt[2][CLEN][16];   // dt rows (cols 0..15)       4 KB
  __shared__ float sB [2][CLEN][8];    // B rows  (cols 16..23)      2 KB
  {
    const float* xf  = xdf + ((size_t)b*LL + s0 )*32;
    const float* xbp = xdb + ((size_t)b*LL + tb0)*32;
    #pragma unroll
    for (int e = threadIdx.x; e < CLEN*16; e += 256){
      int row = e >> 4, col = e & 15;
      sdt[0][row][col] = xf [row*32 + col];
      sdt[1][row][col] = xbp[row*32 + col];
    }
    {
      int e = threadIdx.x;            // CLEN*8 == 256
      int row = e >> 3, col = e & 7;
      sB[0][row][col] = xf [row*32 + 16 + col];
      sB[1][row][col] = xbp[row*32 + 16 + col];
    }
  }
  __syncthreads();

  float4 cwF = ((const float4*)cwf)[d];  float cbF = cbf[d];
  float4 cwB = ((const float4*)cwb)[d];  float cbB = cbb[d];
  const float* dwFp = dtwf + d*RANK;
  const float* dwBp = dtwb + d*RANK;
  float4 wF0 = ((const float4*)dwFp)[0], wF1 = ((const float4*)dwFp)[1];
  float4 wF2 = ((const float4*)dwFp)[2], wF3 = ((const float4*)dwFp)[3];
  float4 wB0 = ((const float4*)dwBp)[0], wB1 = ((const float4*)dwBp)[1];
  float4 wB2 = ((const float4*)dwBp)[2], wB3 = ((const float4*)dwBp)[3];
  float dtbF = dtbf[d], dtbB = dtbb[d];

  unsigned packF[CLEN], packB[CLEN];

  const unsigned short* xp = xin + (size_t)b*LL*DD + d;
  // sliding window: a0=x[s-3], a1=x[s-2], a2=x[s-1], a3=x[s]
  float a0, a1, a2, a3;
  a1 = (s0-3 >= 0) ? bf2f(xp[(size_t)(s0-3)*DD]) : 0.f;
  a2 = (s0-2 >= 0) ? bf2f(xp[(size_t)(s0-2)*DD]) : 0.f;
  a3 = (s0-1 >= 0) ? bf2f(xp[(size_t)(s0-1)*DD]) : 0.f;

  #pragma unroll
  for (int i = 0; i < CLEN+3; i++){
    int s = s0 + i;
    a0 = a1; a1 = a2; a2 = a3;
    a3 = (s < LL) ? bf2f(xp[(size_t)s*DD]) : 0.f;
    if (i < CLEN){
      // forward output t = s
      float xc = cbF;
      xc = fmaf(cwF.x, a0, xc); xc = fmaf(cwF.y, a1, xc);
      xc = fmaf(cwF.z, a2, xc); xc = fmaf(cwF.w, a3, xc);
      xc = siluf(xc);
      const float* dt = &sdt[0][i][0];
      float de = dtbF;
      de = fmaf(dt[0],wF0.x, fmaf(dt[1],wF0.y, fmaf(dt[2],wF0.z, fmaf(dt[3],wF0.w, de))));
      de = fmaf(dt[4],wF1.x, fmaf(dt[5],wF1.y, fmaf(dt[6],wF1.z, fmaf(dt[7],wF1.w, de))));
      de = fmaf(dt[8],wF2.x, fmaf(dt[9],wF2.y, fmaf(dt[10],wF2.z, fmaf(dt[11],wF2.w, de))));
      de = fmaf(dt[12],wF3.x, fmaf(dt[13],wF3.y, fmaf(dt[14],wF3.z, fmaf(dt[15],wF3.w, de))));
      de = softplus_fast(de);
      unsigned pk = (unsigned)f2bf(xc) | ((unsigned)f2bf(de) << 16);
      packF[i] = pk;
      xde[((size_t)b*LL + s)*DD + d] = pk;
    }
    if (i >= 3){
      // backward output local index lt in chunk CH-1-cf; t' = tb0 + lt
      int lt = CLEN + 2 - i;
      float xc = cbB;
      xc = fmaf(cwB.x, a3, xc); xc = fmaf(cwB.y, a2, xc);
      xc = fmaf(cwB.z, a1, xc); xc = fmaf(cwB.w, a0, xc);
      xc = siluf(xc);
      const float* dt = &sdt[1][lt][0];
      float de = dtbB;
      de = fmaf(dt[0],wB0.x, fmaf(dt[1],wB0.y, fmaf(dt[2],wB0.z, fmaf(dt[3],wB0.w, de))));
      de = fmaf(dt[4],wB1.x, fmaf(dt[5],wB1.y, fmaf(dt[6],wB1.z, fmaf(dt[7],wB1.w, de))));
      de = fmaf(dt[8],wB2.x, fmaf(dt[9],wB2.y, fmaf(dt[10],wB2.z, fmaf(dt[11],wB2.w, de))));
      de = fmaf(dt[12],wB3.x, fmaf(dt[13],wB3.y, fmaf(dt[14],wB3.z, fmaf(dt[15],wB3.w, de))));
      de = softplus_fast(de);
      unsigned pk = (unsigned)f2bf(xc) | ((unsigned)f2bf(de) << 16);
      packB[lt] = pk;
      xde[((size_t)(BB + b)*LL + (tb0 + lt))*DD + d] = pk;
    }
  }

  // ---- local scans (h from 0) for both chunks ----
  #pragma unroll
  for (int dir = 0; dir < 2; dir++){
    const float* Alog = dir ? Alogb : Alogf;
    int chunk = dir ? (CH-1-cf) : cf;
    float A[NST];
    #pragma unroll
    for (int n = 0; n < NST; n++) A[n] = -__expf(Alog[d*NST + n]);
    float h[NST];
    #pragma unroll
    for (int n = 0; n < NST; n++) h[n] = 0.f;
    float S = 0.f;
    #pragma unroll
    for (int t = 0; t < CLEN; t++){
      unsigned pk = dir ? packB[t] : packF[t];
      float xc = bf2f((unsigned short)(pk & 0xffffu));
      float de = bf2f((unsigned short)(pk >> 16));
      S += de;
      float dux = de * xc;
      const float* Bv = &sB[dir][t][0];
      h[0] = fmaf(__expf(de*A[0]), h[0], dux*Bv[0]);
      h[1] = fmaf(__expf(de*A[1]), h[1], dux*Bv[1]);
      h[2] = fmaf(__expf(de*A[2]), h[2], dux*Bv[2]);
      h[3] = fmaf(__expf(de*A[3]), h[3], dux*Bv[3]);
      h[4] = fmaf(__expf(de*A[4]), h[4], dux*Bv[4]);
      h[5] = fmaf(__expf(de*A[5]), h[5], dux*Bv[5]);
      h[6] = fmaf(__expf(de*A[6]), h[6], dux*Bv[6]);
      h[7] = fmaf(__expf(de*A[7]), h[7], dux*Bv[7]);
    }
    size_t ob = ((((size_t)dir*CH + chunk)*BB + b)*DD + d)*NST;
    float4 p0, p1h, h0v, h1v;
    p0.x = __expf(A[0]*S); p0.y = __expf(A[1]*S); p0.z = __expf(A[2]*S); p0.w = __expf(A[3]*S);
    p1h.x= __expf(A[4]*S); p1h.y= __expf(A[5]*S); p1h.z= __expf(A[6]*S); p1h.w= __expf(A[7]*S);
    h0v.x=h[0]; h0v.y=h[1]; h0v.z=h[2]; h0v.w=h[3];
    h1v.x=h[4]; h1v.y=h[5]; h1v.z=h[6]; h1v.w=h[7];
    *(float4*)&P[ob]      = p0;  *(float4*)&P[ob+4]    = p1h;
    *(float4*)&Hout[ob]   = h0v; *(float4*)&Hout[ob+4] = h1v;
  }
}

// Phase 2: sequential carry over CH chunks, 256 blocks x 64 threads,
// 8-deep prefetch. Hin aliases P (same-thread read-then-write, disjoint indices).
__global__ __launch_bounds__(64) void scan_p2(
    const float* P, const float* __restrict__ Hout, float* Hin)
{
  int tid = blockIdx.x*64 + threadIdx.x;   // 0..16383
  int dir = tid >> 13;
  int b   = (tid >> 11) & 3;
  int dn  = tid & 2047;
  const size_t stride = (size_t)BB*2048;
  size_t idx0 = (((size_t)dir*CH)*BB + b)*2048 + dn;

  const int U = 8;
  float pp[U], hh[U];
  #pragma unroll
  for (int u = 0; u < U; u++){
    pp[u] = P[idx0 + u*stride];
    hh[u] = Hout[idx0 + u*stride];
  }
  float h = 0.f;
  for (int c0 = 0; c0 < CH; c0 += U){
    float np[U], nh[U];
    if (c0 + U < CH){
      #pragma unroll
      for (int u = 0; u < U; u++){
        np[u] = P[idx0 + (size_t)(c0+U+u)*stride];
        nh[u] = Hout[idx0 + (size_t)(c0+U+u)*stride];
      }
    }
    #pragma unroll
    for (int u = 0; u < U; u++){
      Hin[idx0 + (size_t)(c0+u)*stride] = h;
      h = fmaf(pp[u], h, hh[u]);
    }
    if (c0 + U < CH){
      #pragma unroll
      for (int u = 0; u < U; u++){ pp[u] = np[u]; hh[u] = nh[u]; }
    }
  }
}

// Phase 3: read packed (xc,de), seeded scan, emit y (bf16).
__global__ __launch_bounds__(256) void scan_p3(
    const unsigned int* __restrict__ xde,
    const float* __restrict__ xdf, const float* __restrict__ xdb,
    const float* __restrict__ Alogf, const float* __restrict__ Alogb,
    const float* __restrict__ Dfp, const float* __restrict__ Dbp,
    const float* Hin,
    unsigned short* __restrict__ yf, unsigned short* __restrict__ yb)
{
  int chunk = blockIdx.x, b = blockIdx.y, dir = blockIdx.z;
  const float* xd   = dir ? xdb : xdf;
  const float* Alog = dir ? Alogb : Alogf;
  int d = threadIdx.x;

  __shared__ float sBC[CLEN*16];   // 2 KB: B (0..7) and C (8..15) per step
  {
    const float* xdp = xd + ((size_t)b*LL + (size_t)chunk*CLEN)*32;
    #pragma unroll
    for (int e = threadIdx.x; e < CLEN*16; e += 256){
      int row = e >> 4, col = e & 15;
      sBC[e] = xdp[row*32 + 16 + col];
    }
  }
  __syncthreads();

  float A[NST];
  #pragma unroll
  for (int n = 0; n < NST; n++) A[n] = -__expf(Alog[d*NST + n]);
  float Dd = (dir ? Dbp : Dfp)[d];

  float h[NST];
  {
    size_t ib = ((((size_t)dir*CH + chunk)*BB + b)*DD + d)*NST;
    float4 a0 = *(const float4*)&Hin[ib];
    float4 a1 = *(const float4*)&Hin[ib+4];
    h[0]=a0.x; h[1]=a0.y; h[2]=a0.z; h[3]=a0.w;
    h[4]=a1.x; h[5]=a1.y; h[6]=a1.z; h[7]=a1.w;
  }

  int base = chunk*CLEN;
  const unsigned int* xdep = xde + ((size_t)(dir*BB + b)*LL + base)*DD + d;
  unsigned short* yp = (dir ? yb : yf) + ((size_t)b*LL + base)*DD + d;

  const int U = 8;
  unsigned int pk[U];
  #pragma unroll
  for (int u = 0; u < U; u++) pk[u] = xdep[(size_t)u*DD];

  for (int t0 = 0; t0 < CLEN; t0 += U){
    unsigned int nk[U];
    if (t0 + U < CLEN){
      #pragma unroll
      for (int u = 0; u < U; u++) nk[u] = xdep[(size_t)(t0+U+u)*DD];
    }
    #pragma unroll
    for (int u = 0; u < U; u++){
      int t = t0 + u;
      float xc = bf2f((unsigned short)(pk[u] & 0xffffu));
      float de = bf2f((unsigned short)(pk[u] >> 16));
      float dux = de * xc;
      const float4 Bv0 = *(const float4*)&sBC[t*16 + 0];
      const float4 Bv1 = *(const float4*)&sBC[t*16 + 4];
      const float4 Cv0 = *(const float4*)&sBC[t*16 + 8];
      const float4 Cv1 = *(const float4*)&sBC[t*16 + 12];
      float acc = xc * Dd;
      h[0] = fmaf(__expf(de*A[0]), h[0], dux*Bv0.x); acc = fmaf(h[0], Cv0.x, acc);
      h[1] = fmaf(__expf(de*A[1]), h[1], dux*Bv0.y); acc = fmaf(h[1], Cv0.y, acc);
      h[2] = fmaf(__expf(de*A[2]), h[2], dux*Bv0.z); acc = fmaf(h[2], Cv0.z, acc);
      h[3] = fmaf(__expf(de*A[3]), h[3], dux*Bv0.w); acc = fmaf(h[3], Cv0.w, acc);
      h[4] = fmaf(__expf(de*A[4]), h[4], dux*Bv1.x); acc = fmaf(h[4], Cv1.x, acc);
      h[5] = fmaf(__expf(de*A[5]), h[5], dux*Bv1.y); acc = fmaf(h[5], Cv1.y, acc);
      h[6] = fmaf(__expf(de*A[6]), h[6], dux*Bv1.z); acc = fmaf(h[6], Cv1.z, acc);
      h[7] = fmaf(__expf(de*A[7]), h[7], dux*Bv1.w); acc = fmaf(h[7], Cv1.w, acc);
      yp[(size_t)t*DD] = f2bf(acc);
    }
    if (t0 + U < CLEN){
      #pragma unroll
      for (int u = 0; u < U; u++) pk[u] = nk[u];
    }
  }
}

// ---------------- Combine: y=(yf+flip(yb))/2 -> rmsnorm -> *silu(z) -> bf16 ------
__global__ __launch_bounds__(64) void combine_kernel(
    const unsigned short* __restrict__ yf, const unsigned short* __restrict__ yb,
    const unsigned short* __restrict__ zb, const float* __restrict__ wn,
    unsigned short* __restrict__ outb)
{
  size_t tok = blockIdx.x;
  int b = (int)(tok / LL), t = (int)(tok % LL);
  int lane = threadIdx.x;
  ushort4 au = ((const ushort4*)(yf + tok*DD))[lane];
  ushort4 cu = ((const ushort4*)(yb + ((size_t)b*LL + (LL-1-t))*DD))[lane];
  float4 v;
  v.x=(bf2f(au.x)+bf2f(cu.x))*0.5f; v.y=(bf2f(au.y)+bf2f(cu.y))*0.5f;
  v.z=(bf2f(au.z)+bf2f(cu.z))*0.5f; v.w=(bf2f(au.w)+bf2f(cu.w))*0.5f;
  float s = v.x*v.x + v.y*v.y + v.z*v.z + v.w*v.w;
  #pragma unroll
  for (int m = 1; m < 64; m <<= 1) s += __shfl_xor(s, m, 64);
  float scale = 1.f / (sqrtf(s)*(1.f/16.f) + 1e-6f);
  float4 wv = ((const float4*)wn)[lane];
  ushort4 zv = ((const ushort4*)(zb + tok*DD))[lane];
  ushort4 r;
  r.x = f2bf(v.x*scale*wv.x*siluf(bf2f(zv.x)));
  r.y = f2bf(v.y*scale*wv.y*siluf(bf2f(zv.y)));
  r.z = f2bf(v.z*scale*wv.z*siluf(bf2f(zv.z)));
  r.w = f2bf(v.w*scale*wv.w*siluf(bf2f(zv.w)));
  ((ushort4*)(outb + tok*DD))[lane] = r;
}

// ---------------- FF depthwise conv k=3 pad(1,1) + SiLU -> bf16 ------------------
__global__ __launch_bounds__(256) void dwconv3_kernel(
    const float* __restrict__ m, const float* __restrict__ w,
    const float* __restrict__ bi, unsigned short* __restrict__ o)
{
  size_t gid = (size_t)blockIdx.x*256 + threadIdx.x;  // over BL*HID
  int c = (int)(gid % HID);
  int tok = (int)(gid / HID);
  int b = tok / LL, t = tok % LL;
  float acc = bi[c];
  #pragma unroll
  for (int k = 0; k < 3; k++){
    int tt = t - 1 + k;
    if (tt >= 0 && tt < LL)
      acc = fmaf(w[c*3 + k], m[((size_t)b*LL + tt)*HID + c], acc);
  }
  o[gid] = f2bf(siluf(acc));
}

extern "C" void kernel_launch(void* const* d_in, const int* in_sizes, int n_in,
                              void* d_out, int out_size, void* d_ws, size_t ws_size,
                              hipStream_t stream)
{
  const float* x0        = (const float*)d_in[0];
  const float* x1        = (const float*)d_in[1];
  const float* w_norm0   = (const float*)d_in[2];
  const float* w_norm1   = (const float*)d_in[3];
  const float* in_proj_w = (const float*)d_in[4];
  const float* conv_w_f  = (const float*)d_in[5];
  const float* conv_b_f  = (const float*)d_in[6];
  const float* xproj_w_f = (const float*)d_in[7];
  const float* dtproj_w_f= (const float*)d_in[8];
  const float* dtproj_b_f= (const float*)d_in[9];
  const float* A_log_f   = (const float*)d_in[10];
  const float* D_f       = (const float*)d_in[11];
  const float* conv_w_bw = (const float*)d_in[12];
  const float* conv_b_bw = (const float*)d_in[13];
  const float* xproj_w_bw= (const float*)d_in[14];
  const float* dtproj_w_bw=(const float*)d_in[15];
  const float* dtproj_b_bw=(const float*)d_in[16];
  const float* A_log_bw  = (const float*)d_in[17];
  const float* D_bw      = (const float*)d_in[18];
  const float* norm_y_w  = (const float*)d_in[19];
  const float* out_proj_w= (const float*)d_in[20];
  const float* fc1_w     = (const float*)d_in[21];
  const float* dw_w      = (const float*)d_in[22];
  const float* dw_b      = (const float*)d_in[23];
  const float* fc2_w     = (const float*)d_in[24];
  float* out = (float*)d_out;
  float* ws  = (float*)d_ws;

  // region map (floats), lifetime-reused
  float* r0 = ws + 0*BLD;   // h0b (bf16) -> yfb (bf16)
  float* r1 = ws + 1*BLD;   // h1 (fp32)  -> ybb (bf16)
  float* r2 = ws + 2*BLD;   // xin_b (bf16, live until front) -> ycomb_b (bf16)
  float* r3 = ws + 3*BLD;   // zb (bf16, live until combine)
  float* r4 = ws + 4*BLD;   // xde (uint32, spans r4+r5) -> m1 (fp32)
  float* r5 = ws + 5*BLD;   //                           -> m2b (bf16)
  float* r6 = ws + 6*BLD;   // wbuf1 (bf16) -> P/Hout carries (Hin aliases P)
  float* r7 = ws + 7*BLD;   // wbuf2 (bf16 weights) + xb (bf16)
  float* xdf  = ws + 8*BLD;            // BL*32
  float* xdb  = ws + 8*BLD + (size_t)BL*32;

  unsigned short* h0b   = (unsigned short*)r0;
  float*          h1    = r1;
  unsigned short* xin_b = (unsigned short*)r2;
  unsigned short* zb    = (unsigned short*)r3;
  unsigned int*   xde   = (unsigned int*)r4;     // 2*BLD dwords = r4+r5
  unsigned short* wbuf1 = (unsigned short*)r6;   // 131072
  unsigned short* yfb   = (unsigned short*)r0;
  unsigned short* ybb   = (unsigned short*)r1;
  const size_t CARRY = (size_t)2*CH*BB*DD*NST;   // 2,097,152 floats (8 MB)
  float* Pbuf = r6;
  float* Hout = r6 + CARRY;
  float* Hin  = Pbuf;                            // aliased; p2 reads-then-writes
  unsigned short* ycomb_b = (unsigned short*)r2;
  unsigned short* wbuf2   = (unsigned short*)r7;
  unsigned short* wb_out  = wbuf2;            // 65536
  unsigned short* wb_fc1  = wbuf2 + 65536;    // 32768
  unsigned short* wb_fc2  = wbuf2 + 98304;    // 32768
  unsigned short* xb      = wbuf2 + 131072;   // BLD bf16
  float*          m1      = r4;
  unsigned short* m2b     = (unsigned short*)r5;

  // 0. weight conversions
  cvt1_kernel<<<dim3(512), 256, 0, stream>>>(in_proj_w, wbuf1, 131072);
  cvt3_kernel<<<dim3(512), 256, 0, stream>>>(out_proj_w, fc1_w, fc2_w, wbuf2);

  // 1. RMSNorm x0 -> h0b (bf16), x1 -> h1 (fp32)
  rms_kernel<<<dim3(BL,2), 64, 0, stream>>>(x0, w_norm0, h0b, x1, w_norm1, h1);

  // 2. xz = h0 @ in_proj_w.T -> xin_b (bf16), zb (bf16)
  gemm_mfma<3><<<dim3(BL/64, 4), 256, 0, stream>>>(
      h0b, wbuf1, nullptr, nullptr, xin_b, BL, 256, 256);
  gemm_mfma<3><<<dim3(BL/64, 4), 256, 0, stream>>>(
      h0b, wbuf1 + 65536, nullptr, nullptr, zb, BL, 256, 256);

  // 3. x_dbl = ctx @ xproj.T (fp32; forward h1, backward flipped h1)
  gemm_abt<64,32,16,4,2><<<dim3(BL/64,1), 256, 0, stream>>>(
      h1, xproj_w_f, xdf, BL, 32, 256, 256, 0);
  gemm_abt<64,32,16,4,2><<<dim3(BL/64,1), 256, 0, stream>>>(
      h1, xproj_w_bw, xdb, BL, 32, 256, 256, 1);

  // 4. fused front: conv+silu+delta both dirs + local scans -> xde, P, Hout
  front_kernel<<<dim3(CH, BB), 256, 0, stream>>>(
      xin_b, xdf, xdb, conv_w_f, conv_b_f, conv_w_bw, conv_b_bw,
      dtproj_w_f, dtproj_b_f, dtproj_w_bw, dtproj_b_bw,
      A_log_f, A_log_bw, xde, Pbuf, Hout);

  // 5-6. carry + seeded re-scan
  scan_p2<<<dim3(256), 64, 0, stream>>>(Pbuf, Hout, Hin);
  scan_p3<<<dim3(CH,BB,2), 256, 0, stream>>>(
      xde, xdf, xdb, A_log_f, A_log_bw, D_f, D_bw, Hin, yfb, ybb);

  // 7. combine + rmsnorm + gate -> bf16 (r2; xin dead)
  combine_kernel<<<dim3(BL), 64, 0, stream>>>(yfb, ybb, zb, norm_y_w, ycomb_b);

  // 8. x = y @ out_proj.T + residual(x0) -> d_out (fp32) + xb (bf16)
  gemm_mfma<1><<<dim3(BL/64, 4), 256, 0, stream>>>(
      ycomb_b, wb_out, out, x0, xb, BL, 256, 256);

  // 9. m1 = x @ fc1.T (fp32; overwrites dead xde)
  gemm_mfma<0><<<dim3(BL/64, 2), 256, 0, stream>>>(
      xb, wb_fc1, m1, nullptr, nullptr, BL, 128, 256);

  // 10. m2 = silu(dwconv3(m1)) -> bf16
  dwconv3_kernel<<<dim3((BL*HID)/256), 256, 0, stream>>>(m1, dw_w, dw_b, m2b);

  // 11. out = x + m2 @ fc2.T
  gemm_mfma<2><<<dim3(BL/64, 4), 256, 0, stream>>>(
      m2b, wb_fc2, out, out, nullptr, BL, 256, 128);
}

// Round 8
// 262.035 us; speedup vs baseline: 1.2737x; 1.2737x over previous
//
#include <hip/hip_runtime.h>
#include <math.h>
#include <cstddef>

#define BB 4
#define LL 4096
#define DD 256
#define NST 8
#define RANK 16
#define HID 128
#define BL (BB*LL)          // 16384
#define BLD ((size_t)BL*DD) // 4194304
#define CH 128              // scan chunks
#define CLEN 32             // steps per chunk (CH*CLEN == LL)
#define XZS 512             // xz row stride (xin cols 0..255, z cols 256..511)

typedef __bf16 bf16x8 __attribute__((ext_vector_type(8)));
typedef float  f32x4  __attribute__((ext_vector_type(4)));

__device__ __forceinline__ float siluf(float x){ return x / (1.f + __expf(-x)); }
__device__ __forceinline__ float softplus_fast(float x){
  float r = __logf(1.f + __expf(x));
  return x > 15.f ? x : r;
}
// fp32 -> bf16 bits, round-to-nearest-even
__device__ __forceinline__ unsigned short f2bf(float x){
  union { float f; unsigned u; } v; v.f = x;
  unsigned r = v.u + 0x7fffu + ((v.u >> 16) & 1u);
  return (unsigned short)(r >> 16);
}
__device__ __forceinline__ float bf2f(unsigned short u){
  union { unsigned u32; float f; } c; c.u32 = ((unsigned)u) << 16;
  return c.f;
}

// ---------------- RMSNorm: both streams -> bf16 ----------------------------------
__global__ __launch_bounds__(64) void rms_kernel(
    const float* __restrict__ x0, const float* __restrict__ w0, unsigned short* __restrict__ o0b,
    const float* __restrict__ x1, const float* __restrict__ w1, unsigned short* __restrict__ o1b)
{
  const float* x; const float* w; unsigned short* o;
  if (blockIdx.y == 0){ x = x0; w = w0; o = o0b; } else { x = x1; w = w1; o = o1b; }
  size_t tok = blockIdx.x;
  int lane = threadIdx.x;
  float4 v = ((const float4*)(x + tok*DD))[lane];
  float s = v.x*v.x + v.y*v.y + v.z*v.z + v.w*v.w;
  #pragma unroll
  for (int m = 1; m < 64; m <<= 1) s += __shfl_xor(s, m, 64);
  float scale = 1.f / (sqrtf(s) * (1.f/16.f) + 1e-6f);
  float4 wv = ((const float4*)w)[lane];
  ushort4 r;
  r.x = f2bf(v.x*scale*wv.x); r.y = f2bf(v.y*scale*wv.y);
  r.z = f2bf(v.z*scale*wv.z); r.w = f2bf(v.w*scale*wv.w);
  ((ushort4*)(o + tok*DD))[lane] = r;
}

// ---------------- weight fp32->bf16 conversion -----------------------------------
__global__ __launch_bounds__(256) void cvt1_kernel(
    const float* __restrict__ s, unsigned short* __restrict__ d, int n)
{
  int i = blockIdx.x*256 + threadIdx.x;
  if (i < n) d[i] = f2bf(s[i]);
}
// xproj_f(8192) | xproj_bw(8192) | out_proj(65536) | fc1(32768) | fc2(32768)
__global__ __launch_bounds__(256) void cvt5_kernel(
    const float* __restrict__ s0, const float* __restrict__ s1,
    const float* __restrict__ s2, const float* __restrict__ s3,
    const float* __restrict__ s4, unsigned short* __restrict__ d)
{
  int i = blockIdx.x*256 + threadIdx.x;   // 0..147455
  if (i >= 147456) return;
  float v;
  if (i < 8192)        v = s0[i];
  else if (i < 16384)  v = s1[i - 8192];
  else if (i < 81920)  v = s2[i - 16384];
  else if (i < 114688) v = s3[i - 81920];
  else                 v = s4[i - 114688];
  d[i] = f2bf(v);
}

// ---------------- bf16 MFMA GEMM, 64x64 tile: C = A @ Bw^T (+ epilogue) ----------
// EPI: 0 = C=acc ; 1 = C=acc+Add & Cb=bf16(C) ; 2 = C=acc+Add ; 3 = Cb=bf16(acc)
// ldc = row stride of C/Cb/Add (for writing into a wider matrix)
template<int EPI>
__global__ __launch_bounds__(256) void gemm_mfma(
    const unsigned short* __restrict__ A, const unsigned short* __restrict__ Bw,
    float* __restrict__ C, const float* __restrict__ Add,
    unsigned short* __restrict__ Cb, int M, int ldc, int K)
{
  constexpr int BK = 32, PAD = 8;
  __shared__ __align__(16) unsigned short As[64][BK+PAD];
  __shared__ __align__(16) unsigned short Bs[64][BK+PAD];
  int tid  = threadIdx.x;
  int row0 = blockIdx.x * 64;
  int col0 = blockIdx.y * 64;
  int wave = tid >> 6, lane = tid & 63;
  int wm = (wave >> 1) * 32, wn = (wave & 1) * 32;
  int lm = lane & 15, kq = lane >> 4;
  int sr = tid >> 2, sc8 = (tid & 3) * 8;

  f32x4 acc[2][2];
  #pragma unroll
  for (int i = 0; i < 2; i++)
    #pragma unroll
    for (int j = 0; j < 2; j++) acc[i][j] = (f32x4){0.f,0.f,0.f,0.f};

  for (int k0 = 0; k0 < K; k0 += BK){
    *(int4*)&As[sr][sc8] = *(const int4*)&A [(size_t)(row0 + sr)*K + k0 + sc8];
    *(int4*)&Bs[sr][sc8] = *(const int4*)&Bw[(size_t)(col0 + sr)*K + k0 + sc8];
    __syncthreads();
    bf16x8 af[2], bfv[2];
    #pragma unroll
    for (int i = 0; i < 2; i++) af[i]  = *(const bf16x8*)&As[wm + i*16 + lm][kq*8];
    #pragma unroll
    for (int j = 0; j < 2; j++) bfv[j] = *(const bf16x8*)&Bs[wn + j*16 + lm][kq*8];
    #pragma unroll
    for (int i = 0; i < 2; i++)
      #pragma unroll
      for (int j = 0; j < 2; j++)
        acc[i][j] = __builtin_amdgcn_mfma_f32_16x16x32_bf16(af[i], bfv[j], acc[i][j], 0, 0, 0);
    __syncthreads();
  }

  // C/D layout: col = lane&15, row = (lane>>4)*4 + reg   [m89-verified]
  #pragma unroll
  for (int i = 0; i < 2; i++){
    int rbase = row0 + wm + i*16 + kq*4;
    #pragma unroll
    for (int j = 0; j < 2; j++){
      int col = col0 + wn + j*16 + lm;
      #pragma unroll
      for (int r = 0; r < 4; r++){
        size_t idx = (size_t)(rbase + r)*ldc + col;
        float v = acc[i][j][r];
        if constexpr (EPI == 1 || EPI == 2) v += Add[idx];
        if constexpr (EPI != 3) C[idx] = v;
        if constexpr (EPI == 1 || EPI == 3) Cb[idx] = f2bf(v);
      }
    }
  }
}

// =================== Front: conv+silu+delta + local scan (per direction) =========
// Block = (chunk, b, dir). Reads xin (from xz, stride XZS) once via sliding
// window; dt/B staged in LDS from merged xd (natural t order; backward rows
// at LL-1-pos). Writes packed (xc,de) -> xde and local-scan P, Hout.
__global__ __launch_bounds__(256) void front_kernel(
    const unsigned short* __restrict__ xz,
    const float* __restrict__ xd,
    const float* __restrict__ cwf, const float* __restrict__ cbf,
    const float* __restrict__ cwb, const float* __restrict__ cbb,
    const float* __restrict__ dtwf, const float* __restrict__ dtbf,
    const float* __restrict__ dtwb, const float* __restrict__ dtbb,
    const float* __restrict__ Alogf, const float* __restrict__ Alogb,
    unsigned int* __restrict__ xde,
    float* __restrict__ P, float* __restrict__ Hout)
{
  int chunk = blockIdx.x, b = blockIdx.y, dir = blockIdx.z;
  int s0 = chunk*CLEN;
  int d  = threadIdx.x;

  __shared__ float sdt[CLEN][16];   // 2 KB
  __shared__ float sB [CLEN][8];    // 1 KB
  {
    #pragma unroll
    for (int e = threadIdx.x; e < CLEN*16; e += 256){
      int lt = e >> 4, col = e & 15;
      int pos = s0 + lt;
      int row = dir ? (LL-1-pos) : pos;
      sdt[lt][col] = xd[((size_t)b*LL + row)*64 + dir*32 + col];
    }
    {
      int e = threadIdx.x;   // CLEN*8 == 256
      int lt = e >> 3, col = e & 7;
      int pos = s0 + lt;
      int row = dir ? (LL-1-pos) : pos;
      sB[lt][col] = xd[((size_t)b*LL + row)*64 + dir*32 + 16 + col];
    }
  }
  __syncthreads();

  float4 cw = ((const float4*)(dir ? cwb : cwf))[d];
  float cb  = (dir ? cbb : cbf)[d];
  const float* dtw = (dir ? dtwb : dtwf) + d*RANK;
  float4 w0 = ((const float4*)dtw)[0], w1 = ((const float4*)dtw)[1];
  float4 w2 = ((const float4*)dtw)[2], w3 = ((const float4*)dtw)[3];
  float dtb = (dir ? dtbb : dtbf)[d];

  const unsigned short* xp = xz + (size_t)b*LL*XZS + d;
  #define LDX(pos) ((pos) >= 0 ? bf2f(xp[(size_t)(dir ? (LL-1-(pos)) : (pos))*XZS]) : 0.f)

  float a0, a1, a2, a3;
  a1 = LDX(s0-3); a2 = LDX(s0-2); a3 = LDX(s0-1);

  unsigned packX[CLEN];
  const int U = 8;
  float px[U];
  #pragma unroll
  for (int u = 0; u < U; u++) px[u] = LDX(s0+u);

  for (int g = 0; g < CLEN; g += U){
    float nx[U];
    if (g + U < CLEN){
      #pragma unroll
      for (int u = 0; u < U; u++) nx[u] = LDX(s0+g+U+u);
    }
    #pragma unroll
    for (int u = 0; u < U; u++){
      int i = g + u;
      a0 = a1; a1 = a2; a2 = a3; a3 = px[u];
      float xc = cb;
      xc = fmaf(cw.x, a0, xc); xc = fmaf(cw.y, a1, xc);
      xc = fmaf(cw.z, a2, xc); xc = fmaf(cw.w, a3, xc);
      xc = siluf(xc);
      const float* dt = &sdt[i][0];
      float de = dtb;
      de = fmaf(dt[0],w0.x, fmaf(dt[1],w0.y, fmaf(dt[2],w0.z, fmaf(dt[3],w0.w, de))));
      de = fmaf(dt[4],w1.x, fmaf(dt[5],w1.y, fmaf(dt[6],w1.z, fmaf(dt[7],w1.w, de))));
      de = fmaf(dt[8],w2.x, fmaf(dt[9],w2.y, fmaf(dt[10],w2.z, fmaf(dt[11],w2.w, de))));
      de = fmaf(dt[12],w3.x, fmaf(dt[13],w3.y, fmaf(dt[14],w3.z, fmaf(dt[15],w3.w, de))));
      de = softplus_fast(de);
      unsigned pk = (unsigned)f2bf(xc) | ((unsigned)f2bf(de) << 16);
      packX[i] = pk;
      xde[((size_t)(dir*BB + b)*LL + (s0+i))*DD + d] = pk;
    }
    if (g + U < CLEN){
      #pragma unroll
      for (int u = 0; u < U; u++) px[u] = nx[u];
    }
  }
  #undef LDX

  // ---- local scan (h from 0) ----
  const float* Alog = dir ? Alogb : Alogf;
  float A[NST];
  #pragma unroll
  for (int n = 0; n < NST; n++) A[n] = -__expf(Alog[d*NST + n]);
  float h[NST];
  #pragma unroll
  for (int n = 0; n < NST; n++) h[n] = 0.f;
  float S = 0.f;
  #pragma unroll
  for (int t = 0; t < CLEN; t++){
    unsigned pk = packX[t];
    float xc = bf2f((unsigned short)(pk & 0xffffu));
    float de = bf2f((unsigned short)(pk >> 16));
    S += de;
    float dux = de * xc;
    const float* Bv = &sB[t][0];
    h[0] = fmaf(__expf(de*A[0]), h[0], dux*Bv[0]);
    h[1] = fmaf(__expf(de*A[1]), h[1], dux*Bv[1]);
    h[2] = fmaf(__expf(de*A[2]), h[2], dux*Bv[2]);
    h[3] = fmaf(__expf(de*A[3]), h[3], dux*Bv[3]);
    h[4] = fmaf(__expf(de*A[4]), h[4], dux*Bv[4]);
    h[5] = fmaf(__expf(de*A[5]), h[5], dux*Bv[5]);
    h[6] = fmaf(__expf(de*A[6]), h[6], dux*Bv[6]);
    h[7] = fmaf(__expf(de*A[7]), h[7], dux*Bv[7]);
  }
  size_t ob = ((((size_t)dir*CH + chunk)*BB + b)*DD + d)*NST;
  float4 p0, p1h, h0v, h1v;
  p0.x = __expf(A[0]*S); p0.y = __expf(A[1]*S); p0.z = __expf(A[2]*S); p0.w = __expf(A[3]*S);
  p1h.x= __expf(A[4]*S); p1h.y= __expf(A[5]*S); p1h.z= __expf(A[6]*S); p1h.w= __expf(A[7]*S);
  h0v.x=h[0]; h0v.y=h[1]; h0v.z=h[2]; h0v.w=h[3];
  h1v.x=h[4]; h1v.y=h[5]; h1v.z=h[6]; h1v.w=h[7];
  *(float4*)&P[ob]      = p0;  *(float4*)&P[ob+4]    = p1h;
  *(float4*)&Hout[ob]   = h0v; *(float4*)&Hout[ob+4] = h1v;
}

// Phase 2: sequential carry, 256 blocks x 64 threads, 8-deep prefetch.
// Hin aliases P (same-thread read-then-write, disjoint indices).
__global__ __launch_bounds__(64) void scan_p2(
    const float* P, const float* __restrict__ Hout, float* Hin)
{
  int tid = blockIdx.x*64 + threadIdx.x;   // 0..16383
  int dir = tid >> 13;
  int b   = (tid >> 11) & 3;
  int dn  = tid & 2047;
  const size_t stride = (size_t)BB*2048;
  size_t idx0 = (((size_t)dir*CH)*BB + b)*2048 + dn;

  const int U = 8;
  float pp[U], hh[U];
  #pragma unroll
  for (int u = 0; u < U; u++){
    pp[u] = P[idx0 + u*stride];
    hh[u] = Hout[idx0 + u*stride];
  }
  float h = 0.f;
  for (int c0 = 0; c0 < CH; c0 += U){
    float np[U], nh[U];
    if (c0 + U < CH){
      #pragma unroll
      for (int u = 0; u < U; u++){
        np[u] = P[idx0 + (size_t)(c0+U+u)*stride];
        nh[u] = Hout[idx0 + (size_t)(c0+U+u)*stride];
      }
    }
    #pragma unroll
    for (int u = 0; u < U; u++){
      Hin[idx0 + (size_t)(c0+u)*stride] = h;
      h = fmaf(pp[u], h, hh[u]);
    }
    if (c0 + U < CH){
      #pragma unroll
      for (int u = 0; u < U; u++){ pp[u] = np[u]; hh[u] = nh[u]; }
    }
  }
}

// Phase 3: read packed (xc,de), seeded scan, emit y (bf16).
__global__ __launch_bounds__(256) void scan_p3(
    const unsigned int* __restrict__ xde,
    const float* __restrict__ xd,
    const float* __restrict__ Alogf, const float* __restrict__ Alogb,
    const float* __restrict__ Dfp, const float* __restrict__ Dbp,
    const float* Hin,
    unsigned short* __restrict__ yf, unsigned short* __restrict__ yb)
{
  int chunk = blockIdx.x, b = blockIdx.y, dir = blockIdx.z;
  const float* Alog = dir ? Alogb : Alogf;
  int d = threadIdx.x;
  int base = chunk*CLEN;

  __shared__ float sBC[CLEN*16];   // 2 KB: B (0..7) and C (8..15) per step
  {
    #pragma unroll
    for (int e = threadIdx.x; e < CLEN*16; e += 256){
      int lt = e >> 4, col = e & 15;
      int pos = base + lt;
      int row = dir ? (LL-1-pos) : pos;
      sBC[e] = xd[((size_t)b*LL + row)*64 + dir*32 + 16 + col];
    }
  }
  __syncthreads();

  float A[NST];
  #pragma unroll
  for (int n = 0; n < NST; n++) A[n] = -__expf(Alog[d*NST + n]);
  float Dd = (dir ? Dbp : Dfp)[d];

  float h[NST];
  {
    size_t ib = ((((size_t)dir*CH + chunk)*BB + b)*DD + d)*NST;
    float4 a0 = *(const float4*)&Hin[ib];
    float4 a1 = *(const float4*)&Hin[ib+4];
    h[0]=a0.x; h[1]=a0.y; h[2]=a0.z; h[3]=a0.w;
    h[4]=a1.x; h[5]=a1.y; h[6]=a1.z; h[7]=a1.w;
  }

  const unsigned int* xdep = xde + ((size_t)(dir*BB + b)*LL + base)*DD + d;
  unsigned short* yp = (dir ? yb : yf) + ((size_t)b*LL + base)*DD + d;

  const int U = 8;
  unsigned int pk[U];
  #pragma unroll
  for (int u = 0; u < U; u++) pk[u] = xdep[(size_t)u*DD];

  for (int t0 = 0; t0 < CLEN; t0 += U){
    unsigned int nk[U];
    if (t0 + U < CLEN){
      #pragma unroll
      for (int u = 0; u < U; u++) nk[u] = xdep[(size_t)(t0+U+u)*DD];
    }
    #pragma unroll
    for (int u = 0; u < U; u++){
      int t = t0 + u;
      float xc = bf2f((unsigned short)(pk[u] & 0xffffu));
      float de = bf2f((unsigned short)(pk[u] >> 16));
      float dux = de * xc;
      const float4 Bv0 = *(const float4*)&sBC[t*16 + 0];
      const float4 Bv1 = *(const float4*)&sBC[t*16 + 4];
      const float4 Cv0 = *(const float4*)&sBC[t*16 + 8];
      const float4 Cv1 = *(const float4*)&sBC[t*16 + 12];
      float acc = xc * Dd;
      h[0] = fmaf(__expf(de*A[0]), h[0], dux*Bv0.x); acc = fmaf(h[0], Cv0.x, acc);
      h[1] = fmaf(__expf(de*A[1]), h[1], dux*Bv0.y); acc = fmaf(h[1], Cv0.y, acc);
      h[2] = fmaf(__expf(de*A[2]), h[2], dux*Bv0.z); acc = fmaf(h[2], Cv0.z, acc);
      h[3] = fmaf(__expf(de*A[3]), h[3], dux*Bv0.w); acc = fmaf(h[3], Cv0.w, acc);
      h[4] = fmaf(__expf(de*A[4]), h[4], dux*Bv1.x); acc = fmaf(h[4], Cv1.x, acc);
      h[5] = fmaf(__expf(de*A[5]), h[5], dux*Bv1.y); acc = fmaf(h[5], Cv1.y, acc);
      h[6] = fmaf(__expf(de*A[6]), h[6], dux*Bv1.z); acc = fmaf(h[6], Cv1.z, acc);
      h[7] = fmaf(__expf(de*A[7]), h[7], dux*Bv1.w); acc = fmaf(h[7], Cv1.w, acc);
      yp[(size_t)t*DD] = f2bf(acc);
    }
    if (t0 + U < CLEN){
      #pragma unroll
      for (int u = 0; u < U; u++) pk[u] = nk[u];
    }
  }
}

// ---------------- Combine: y=(yf+flip(yb))/2 -> rmsnorm -> *silu(z) -> bf16 ------
__global__ __launch_bounds__(64) void combine_kernel(
    const unsigned short* __restrict__ yf, const unsigned short* __restrict__ yb,
    const unsigned short* __restrict__ xz, const float* __restrict__ wn,
    unsigned short* __restrict__ outb)
{
  size_t tok = blockIdx.x;
  int b = (int)(tok / LL), t = (int)(tok % LL);
  int lane = threadIdx.x;
  ushort4 au = ((const ushort4*)(yf + tok*DD))[lane];
  ushort4 cu = ((const ushort4*)(yb + ((size_t)b*LL + (LL-1-t))*DD))[lane];
  float4 v;
  v.x=(bf2f(au.x)+bf2f(cu.x))*0.5f; v.y=(bf2f(au.y)+bf2f(cu.y))*0.5f;
  v.z=(bf2f(au.z)+bf2f(cu.z))*0.5f; v.w=(bf2f(au.w)+bf2f(cu.w))*0.5f;
  float s = v.x*v.x + v.y*v.y + v.z*v.z + v.w*v.w;
  #pragma unroll
  for (int m = 1; m < 64; m <<= 1) s += __shfl_xor(s, m, 64);
  float scale = 1.f / (sqrtf(s)*(1.f/16.f) + 1e-6f);
  float4 wv = ((const float4*)wn)[lane];
  ushort4 zv = *(const ushort4*)&xz[tok*XZS + 256 + lane*4];
  ushort4 r;
  r.x = f2bf(v.x*scale*wv.x*siluf(bf2f(zv.x)));
  r.y = f2bf(v.y*scale*wv.y*siluf(bf2f(zv.y)));
  r.z = f2bf(v.z*scale*wv.z*siluf(bf2f(zv.z)));
  r.w = f2bf(v.w*scale*wv.w*siluf(bf2f(zv.w)));
  ((ushort4*)(outb + tok*DD))[lane] = r;
}

// ---------------- FF depthwise conv k=3 pad(1,1) + SiLU -> bf16 ------------------
__global__ __launch_bounds__(256) void dwconv3_kernel(
    const float* __restrict__ m, const float* __restrict__ w,
    const float* __restrict__ bi, unsigned short* __restrict__ o)
{
  size_t gid = (size_t)blockIdx.x*256 + threadIdx.x;  // over BL*HID
  int c = (int)(gid % HID);
  int tok = (int)(gid / HID);
  int b = tok / LL, t = tok % LL;
  float acc = bi[c];
  #pragma unroll
  for (int k = 0; k < 3; k++){
    int tt = t - 1 + k;
    if (tt >= 0 && tt < LL)
      acc = fmaf(w[c*3 + k], m[((size_t)b*LL + tt)*HID + c], acc);
  }
  o[gid] = f2bf(siluf(acc));
}

extern "C" void kernel_launch(void* const* d_in, const int* in_sizes, int n_in,
                              void* d_out, int out_size, void* d_ws, size_t ws_size,
                              hipStream_t stream)
{
  const float* x0        = (const float*)d_in[0];
  const float* x1        = (const float*)d_in[1];
  const float* w_norm0   = (const float*)d_in[2];
  const float* w_norm1   = (const float*)d_in[3];
  const float* in_proj_w = (const float*)d_in[4];
  const float* conv_w_f  = (const float*)d_in[5];
  const float* conv_b_f  = (const float*)d_in[6];
  const float* xproj_w_f = (const float*)d_in[7];
  const float* dtproj_w_f= (const float*)d_in[8];
  const float* dtproj_b_f= (const float*)d_in[9];
  const float* A_log_f   = (const float*)d_in[10];
  const float* D_f       = (const float*)d_in[11];
  const float* conv_w_bw = (const float*)d_in[12];
  const float* conv_b_bw = (const float*)d_in[13];
  const float* xproj_w_bw= (const float*)d_in[14];
  const float* dtproj_w_bw=(const float*)d_in[15];
  const float* dtproj_b_bw=(const float*)d_in[16];
  const float* A_log_bw  = (const float*)d_in[17];
  const float* D_bw      = (const float*)d_in[18];
  const float* norm_y_w  = (const float*)d_in[19];
  const float* out_proj_w= (const float*)d_in[20];
  const float* fc1_w     = (const float*)d_in[21];
  const float* dw_w      = (const float*)d_in[22];
  const float* dw_b      = (const float*)d_in[23];
  const float* fc2_w     = (const float*)d_in[24];
  float* out = (float*)d_out;
  float* ws  = (float*)d_ws;

  // region map (floats, BLD each), lifetime-reused
  float* r0 = ws + 0*BLD;   // h0b (bf16) -> yfb (bf16)
  float* r1 = ws + 1*BLD;   // h1b (bf16) -> ybb (bf16)
  float* r2 = ws + 2*BLD;   // xz_b (bf16, BL x 512 = full region)
  float* r3 = ws + 3*BLD;   // xd (fp32 BLx64, 4MB) ; ycomb_b (bf16, after p3)
  float* r4 = ws + 4*BLD;   // xde (uint32, spans r4+r5) -> m1 (fp32)
  float* r5 = ws + 5*BLD;   //                           -> m2b (bf16)
  float* r6 = ws + 6*BLD;   // wbuf1 (bf16 in_proj) -> P/Hout carries (Hin aliases P)
  float* r7 = ws + 7*BLD;   // wbuf2 (bf16 weights) + xb (bf16)

  unsigned short* h0b   = (unsigned short*)r0;
  unsigned short* h1b   = (unsigned short*)r1;
  unsigned short* xz_b  = (unsigned short*)r2;   // BL x XZS
  float*          xd    = r3;                    // BL x 64 fp32
  unsigned int*   xde   = (unsigned int*)r4;     // 2*BLD dwords = r4+r5
  unsigned short* wbuf1 = (unsigned short*)r6;   // 131072 (512x256)
  unsigned short* yfb   = (unsigned short*)r0;
  unsigned short* ybb   = (unsigned short*)r1;
  const size_t CARRY = (size_t)2*CH*BB*DD*NST;   // 2,097,152 floats (8 MB)
  float* Pbuf = r6;
  float* Hout = r6 + CARRY;
  float* Hin  = Pbuf;                            // aliased; p2 reads-then-writes
  unsigned short* ycomb_b = (unsigned short*)r3; // overwrites dead xd after p3
  unsigned short* wbuf2   = (unsigned short*)r7;
  unsigned short* wb_xp   = wbuf2;               // 16384  (64x256)
  unsigned short* wb_out  = wbuf2 + 16384;       // 65536
  unsigned short* wb_fc1  = wbuf2 + 81920;       // 32768
  unsigned short* wb_fc2  = wbuf2 + 114688;      // 32768
  unsigned short* xb      = wbuf2 + 147456;      // BLD bf16
  float*          m1      = r4;
  unsigned short* m2b     = (unsigned short*)r5;

  // 0. weight conversions
  cvt1_kernel<<<dim3(512), 256, 0, stream>>>(in_proj_w, wbuf1, 131072);
  cvt5_kernel<<<dim3(576), 256, 0, stream>>>(
      xproj_w_f, xproj_w_bw, out_proj_w, fc1_w, fc2_w, wbuf2);

  // 1. RMSNorm x0 -> h0b, x1 -> h1b (both bf16)
  rms_kernel<<<dim3(BL,2), 64, 0, stream>>>(x0, w_norm0, h0b, x1, w_norm1, h1b);

  // 2. xz = h0 @ in_proj.T -> xz_b (bf16, one N=512 dispatch)
  gemm_mfma<3><<<dim3(BL/64, 8), 256, 0, stream>>>(
      h0b, wbuf1, nullptr, nullptr, xz_b, BL, XZS, 256);

  // 3. merged xproj: xd[t][0..31]=fwd dt/B/C, [32..63]=bwd (natural t order)
  gemm_mfma<0><<<dim3(BL/64, 1), 256, 0, stream>>>(
      h1b, wb_xp, xd, nullptr, nullptr, BL, 64, 256);

  // 4. front: conv+silu+delta + local scan (per dir) -> xde, P, Hout
  front_kernel<<<dim3(CH, BB, 2), 256, 0, stream>>>(
      xz_b, xd, conv_w_f, conv_b_f, conv_w_bw, conv_b_bw,
      dtproj_w_f, dtproj_b_f, dtproj_w_bw, dtproj_b_bw,
      A_log_f, A_log_bw, xde, Pbuf, Hout);

  // 5-6. carry + seeded re-scan
  scan_p2<<<dim3(256), 64, 0, stream>>>(Pbuf, Hout, Hin);
  scan_p3<<<dim3(CH,BB,2), 256, 0, stream>>>(
      xde, xd, A_log_f, A_log_bw, D_f, D_bw, Hin, yfb, ybb);

  // 7. combine + rmsnorm + gate -> ycomb_b (r3; xd dead)
  combine_kernel<<<dim3(BL), 64, 0, stream>>>(yfb, ybb, xz_b, norm_y_w, ycomb_b);

  // 8. x = y @ out_proj.T + residual(x0) -> d_out (fp32) + xb (bf16)
  gemm_mfma<1><<<dim3(BL/64, 4), 256, 0, stream>>>(
      ycomb_b, wb_out, out, x0, xb, BL, 256, 256);

  // 9. m1 = x @ fc1.T (fp32; overwrites dead xde)
  gemm_mfma<0><<<dim3(BL/64, 2), 256, 0, stream>>>(
      xb, wb_fc1, m1, nullptr, nullptr, BL, 128, 256);

  // 10. m2 = silu(dwconv3(m1)) -> bf16
  dwconv3_kernel<<<dim3((BL*HID)/256), 256, 0, stream>>>(m1, dw_w, dw_b, m2b);

  // 11. out = x + m2 @ fc2.T
  gemm_mfma<2><<<dim3(BL/64, 4), 256, 0, stream>>>(
      m2b, wb_fc2, out, out, nullptr, BL, 256, 128);
}

// Round 9
// 261.347 us; speedup vs baseline: 1.2771x; 1.0026x over previous
//
#include <hip/hip_runtime.h>
#include <math.h>
#include <cstddef>

#define BB 4
#define LL 4096
#define DD 256
#define NST 8
#define RANK 16
#define HID 128
#define BL (BB*LL)          // 16384
#define BLD ((size_t)BL*DD) // 4194304
#define CH 128              // scan chunks
#define CLEN 32             // steps per chunk (CH*CLEN == LL)
#define XZS 512             // xz row stride (xin cols 0..255, z cols 256..511)

typedef __bf16 bf16x8 __attribute__((ext_vector_type(8)));
typedef float  f32x4  __attribute__((ext_vector_type(4)));

__device__ __forceinline__ float siluf(float x){ return x / (1.f + __expf(-x)); }
__device__ __forceinline__ float softplus_fast(float x){
  float r = __logf(1.f + __expf(x));
  return x > 15.f ? x : r;
}
// fp32 -> bf16 bits, round-to-nearest-even
__device__ __forceinline__ unsigned short f2bf(float x){
  union { float f; unsigned u; } v; v.f = x;
  unsigned r = v.u + 0x7fffu + ((v.u >> 16) & 1u);
  return (unsigned short)(r >> 16);
}
__device__ __forceinline__ float bf2f(unsigned short u){
  union { unsigned u32; float f; } c; c.u32 = ((unsigned)u) << 16;
  return c.f;
}

// ---------------- RMSNorm: both streams -> bf16 ----------------------------------
__global__ __launch_bounds__(64) void rms_kernel(
    const float* __restrict__ x0, const float* __restrict__ w0, unsigned short* __restrict__ o0b,
    const float* __restrict__ x1, const float* __restrict__ w1, unsigned short* __restrict__ o1b)
{
  const float* x; const float* w; unsigned short* o;
  if (blockIdx.y == 0){ x = x0; w = w0; o = o0b; } else { x = x1; w = w1; o = o1b; }
  size_t tok = blockIdx.x;
  int lane = threadIdx.x;
  float4 v = ((const float4*)(x + tok*DD))[lane];
  float s = v.x*v.x + v.y*v.y + v.z*v.z + v.w*v.w;
  #pragma unroll
  for (int m = 1; m < 64; m <<= 1) s += __shfl_xor(s, m, 64);
  float scale = 1.f / (sqrtf(s) * (1.f/16.f) + 1e-6f);
  float4 wv = ((const float4*)w)[lane];
  ushort4 r;
  r.x = f2bf(v.x*scale*wv.x); r.y = f2bf(v.y*scale*wv.y);
  r.z = f2bf(v.z*scale*wv.z); r.w = f2bf(v.w*scale*wv.w);
  ((ushort4*)(o + tok*DD))[lane] = r;
}

// ---------------- weight fp32->bf16 conversion -----------------------------------
__global__ __launch_bounds__(256) void cvt1_kernel(
    const float* __restrict__ s, unsigned short* __restrict__ d, int n)
{
  int i = blockIdx.x*256 + threadIdx.x;
  if (i < n) d[i] = f2bf(s[i]);
}
// xproj_f(8192) | xproj_bw(8192) | out_proj(65536) | fc1(32768) | fc2(32768)
__global__ __launch_bounds__(256) void cvt5_kernel(
    const float* __restrict__ s0, const float* __restrict__ s1,
    const float* __restrict__ s2, const float* __restrict__ s3,
    const float* __restrict__ s4, unsigned short* __restrict__ d)
{
  int i = blockIdx.x*256 + threadIdx.x;   // 0..147455
  if (i >= 147456) return;
  float v;
  if (i < 8192)        v = s0[i];
  else if (i < 16384)  v = s1[i - 8192];
  else if (i < 81920)  v = s2[i - 16384];
  else if (i < 114688) v = s3[i - 81920];
  else                 v = s4[i - 114688];
  d[i] = f2bf(v);
}

// ---------------- bf16 MFMA GEMM, 64x64 tile: C = A @ Bw^T (+ epilogue) ----------
// EPI: 0 = C=acc ; 1 = C=acc+Add & Cb=bf16(C) ; 2 = C=acc+Add ; 3 = Cb=bf16(acc)
// ldc = row stride of C/Cb/Add (for writing into a wider matrix)
template<int EPI>
__global__ __launch_bounds__(256) void gemm_mfma(
    const unsigned short* __restrict__ A, const unsigned short* __restrict__ Bw,
    float* __restrict__ C, const float* __restrict__ Add,
    unsigned short* __restrict__ Cb, int M, int ldc, int K)
{
  constexpr int BK = 32, PAD = 8;
  __shared__ __align__(16) unsigned short As[64][BK+PAD];
  __shared__ __align__(16) unsigned short Bs[64][BK+PAD];
  int tid  = threadIdx.x;
  int row0 = blockIdx.x * 64;
  int col0 = blockIdx.y * 64;
  int wave = tid >> 6, lane = tid & 63;
  int wm = (wave >> 1) * 32, wn = (wave & 1) * 32;
  int lm = lane & 15, kq = lane >> 4;
  int sr = tid >> 2, sc8 = (tid & 3) * 8;

  f32x4 acc[2][2];
  #pragma unroll
  for (int i = 0; i < 2; i++)
    #pragma unroll
    for (int j = 0; j < 2; j++) acc[i][j] = (f32x4){0.f,0.f,0.f,0.f};

  for (int k0 = 0; k0 < K; k0 += BK){
    *(int4*)&As[sr][sc8] = *(const int4*)&A [(size_t)(row0 + sr)*K + k0 + sc8];
    *(int4*)&Bs[sr][sc8] = *(const int4*)&Bw[(size_t)(col0 + sr)*K + k0 + sc8];
    __syncthreads();
    bf16x8 af[2], bfv[2];
    #pragma unroll
    for (int i = 0; i < 2; i++) af[i]  = *(const bf16x8*)&As[wm + i*16 + lm][kq*8];
    #pragma unroll
    for (int j = 0; j < 2; j++) bfv[j] = *(const bf16x8*)&Bs[wn + j*16 + lm][kq*8];
    #pragma unroll
    for (int i = 0; i < 2; i++)
      #pragma unroll
      for (int j = 0; j < 2; j++)
        acc[i][j] = __builtin_amdgcn_mfma_f32_16x16x32_bf16(af[i], bfv[j], acc[i][j], 0, 0, 0);
    __syncthreads();
  }

  // C/D layout: col = lane&15, row = (lane>>4)*4 + reg   [m89-verified]
  #pragma unroll
  for (int i = 0; i < 2; i++){
    int rbase = row0 + wm + i*16 + kq*4;
    #pragma unroll
    for (int j = 0; j < 2; j++){
      int col = col0 + wn + j*16 + lm;
      #pragma unroll
      for (int r = 0; r < 4; r++){
        size_t idx = (size_t)(rbase + r)*ldc + col;
        float v = acc[i][j][r];
        if constexpr (EPI == 1 || EPI == 2) v += Add[idx];
        if constexpr (EPI != 3) C[idx] = v;
        if constexpr (EPI == 1 || EPI == 3) Cb[idx] = f2bf(v);
      }
    }
  }
}

// =================== Front: conv+silu+delta + local scan (per direction) =========
// Block = (chunk, b, dir). Reads xin (from xz, stride XZS) once via sliding
// window; dt/B staged in LDS from merged xd. Writes packed (xc,de) -> xde and
// local-scan P, Hout. FAST path: A[n] == -(n+1) (true for this problem's
// A_log = log(1..8)) -> dA[n] = e1^(n+1), e1 = exp(-de): 1 exp + 7 muls
// instead of 8 exps per step. General path kept as fallback.
__global__ __launch_bounds__(256) void front_kernel(
    const unsigned short* __restrict__ xz,
    const float* __restrict__ xd,
    const float* __restrict__ cwf, const float* __restrict__ cbf,
    const float* __restrict__ cwb, const float* __restrict__ cbb,
    const float* __restrict__ dtwf, const float* __restrict__ dtbf,
    const float* __restrict__ dtwb, const float* __restrict__ dtbb,
    const float* __restrict__ Alogf, const float* __restrict__ Alogb,
    unsigned int* __restrict__ xde,
    float* __restrict__ P, float* __restrict__ Hout)
{
  int chunk = blockIdx.x, b = blockIdx.y, dir = blockIdx.z;
  int s0 = chunk*CLEN;
  int d  = threadIdx.x;

  __shared__ float sdt[CLEN][16];   // 2 KB
  __shared__ float sB [CLEN][8];    // 1 KB
  {
    #pragma unroll
    for (int e = threadIdx.x; e < CLEN*16; e += 256){
      int lt = e >> 4, col = e & 15;
      int pos = s0 + lt;
      int row = dir ? (LL-1-pos) : pos;
      sdt[lt][col] = xd[((size_t)b*LL + row)*64 + dir*32 + col];
    }
    {
      int e = threadIdx.x;   // CLEN*8 == 256
      int lt = e >> 3, col = e & 7;
      int pos = s0 + lt;
      int row = dir ? (LL-1-pos) : pos;
      sB[lt][col] = xd[((size_t)b*LL + row)*64 + dir*32 + 16 + col];
    }
  }
  __syncthreads();

  float4 cw = ((const float4*)(dir ? cwb : cwf))[d];
  float cb  = (dir ? cbb : cbf)[d];
  const float* dtw = (dir ? dtwb : dtwf) + d*RANK;
  float4 w0 = ((const float4*)dtw)[0], w1 = ((const float4*)dtw)[1];
  float4 w2 = ((const float4*)dtw)[2], w3 = ((const float4*)dtw)[3];
  float dtb = (dir ? dtbb : dtbf)[d];

  const unsigned short* xp = xz + (size_t)b*LL*XZS + d;
  #define LDX(pos) ((pos) >= 0 ? bf2f(xp[(size_t)(dir ? (LL-1-(pos)) : (pos))*XZS]) : 0.f)

  float a0, a1, a2, a3;
  a1 = LDX(s0-3); a2 = LDX(s0-2); a3 = LDX(s0-1);

  unsigned packX[CLEN];
  const int U = 8;
  float px[U];
  #pragma unroll
  for (int u = 0; u < U; u++) px[u] = LDX(s0+u);

  for (int g = 0; g < CLEN; g += U){
    float nx[U];
    if (g + U < CLEN){
      #pragma unroll
      for (int u = 0; u < U; u++) nx[u] = LDX(s0+g+U+u);
    }
    #pragma unroll
    for (int u = 0; u < U; u++){
      int i = g + u;
      a0 = a1; a1 = a2; a2 = a3; a3 = px[u];
      float xc = cb;
      xc = fmaf(cw.x, a0, xc); xc = fmaf(cw.y, a1, xc);
      xc = fmaf(cw.z, a2, xc); xc = fmaf(cw.w, a3, xc);
      xc = siluf(xc);
      const float* dt = &sdt[i][0];
      float de = dtb;
      de = fmaf(dt[0],w0.x, fmaf(dt[1],w0.y, fmaf(dt[2],w0.z, fmaf(dt[3],w0.w, de))));
      de = fmaf(dt[4],w1.x, fmaf(dt[5],w1.y, fmaf(dt[6],w1.z, fmaf(dt[7],w1.w, de))));
      de = fmaf(dt[8],w2.x, fmaf(dt[9],w2.y, fmaf(dt[10],w2.z, fmaf(dt[11],w2.w, de))));
      de = fmaf(dt[12],w3.x, fmaf(dt[13],w3.y, fmaf(dt[14],w3.z, fmaf(dt[15],w3.w, de))));
      de = softplus_fast(de);
      unsigned pk = (unsigned)f2bf(xc) | ((unsigned)f2bf(de) << 16);
      packX[i] = pk;
      xde[((size_t)(dir*BB + b)*LL + (s0+i))*DD + d] = pk;
    }
    if (g + U < CLEN){
      #pragma unroll
      for (int u = 0; u < U; u++) px[u] = nx[u];
    }
  }
  #undef LDX

  // ---- local scan (h from 0) ----
  const float* Alog = dir ? Alogb : Alogf;
  float A[NST];
  bool fast = true;
  #pragma unroll
  for (int n = 0; n < NST; n++){
    A[n] = -__expf(Alog[d*NST + n]);
    fast = fast && (fabsf(A[n] + (float)(n+1)) < 1e-3f);
  }
  float h[NST];
  #pragma unroll
  for (int n = 0; n < NST; n++) h[n] = 0.f;
  float S = 0.f;

  if (fast){
    #pragma unroll
    for (int t = 0; t < CLEN; t++){
      unsigned pk = packX[t];
      float xc = bf2f((unsigned short)(pk & 0xffffu));
      float de = bf2f((unsigned short)(pk >> 16));
      S += de;
      float dux = de * xc;
      const float* Bv = &sB[t][0];
      float e1 = __expf(-de);
      float dA = e1;
      h[0] = fmaf(dA, h[0], dux*Bv[0]); dA *= e1;
      h[1] = fmaf(dA, h[1], dux*Bv[1]); dA *= e1;
      h[2] = fmaf(dA, h[2], dux*Bv[2]); dA *= e1;
      h[3] = fmaf(dA, h[3], dux*Bv[3]); dA *= e1;
      h[4] = fmaf(dA, h[4], dux*Bv[4]); dA *= e1;
      h[5] = fmaf(dA, h[5], dux*Bv[5]); dA *= e1;
      h[6] = fmaf(dA, h[6], dux*Bv[6]); dA *= e1;
      h[7] = fmaf(dA, h[7], dux*Bv[7]);
    }
  } else {
    #pragma unroll
    for (int t = 0; t < CLEN; t++){
      unsigned pk = packX[t];
      float xc = bf2f((unsigned short)(pk & 0xffffu));
      float de = bf2f((unsigned short)(pk >> 16));
      S += de;
      float dux = de * xc;
      const float* Bv = &sB[t][0];
      #pragma unroll
      for (int n = 0; n < NST; n++)
        h[n] = fmaf(__expf(de*A[n]), h[n], dux*Bv[n]);
    }
  }

  size_t ob = ((((size_t)dir*CH + chunk)*BB + b)*DD + d)*NST;
  float4 p0, p1h, h0v, h1v;
  if (fast){
    float E = __expf(-S);
    float q = E;
    p0.x = q; q *= E; p0.y = q; q *= E; p0.z = q; q *= E; p0.w = q; q *= E;
    p1h.x= q; q *= E; p1h.y= q; q *= E; p1h.z= q; q *= E; p1h.w= q;
  } else {
    p0.x = __expf(A[0]*S); p0.y = __expf(A[1]*S); p0.z = __expf(A[2]*S); p0.w = __expf(A[3]*S);
    p1h.x= __expf(A[4]*S); p1h.y= __expf(A[5]*S); p1h.z= __expf(A[6]*S); p1h.w= __expf(A[7]*S);
  }
  h0v.x=h[0]; h0v.y=h[1]; h0v.z=h[2]; h0v.w=h[3];
  h1v.x=h[4]; h1v.y=h[5]; h1v.z=h[6]; h1v.w=h[7];
  *(float4*)&P[ob]      = p0;  *(float4*)&P[ob+4]    = p1h;
  *(float4*)&Hout[ob]   = h0v; *(float4*)&Hout[ob+4] = h1v;
}

// Phase 2: sequential carry, 256 blocks x 64 threads, 8-deep prefetch.
// Hin aliases P (same-thread read-then-write, disjoint indices).
__global__ __launch_bounds__(64) void scan_p2(
    const float* P, const float* __restrict__ Hout, float* Hin)
{
  int tid = blockIdx.x*64 + threadIdx.x;   // 0..16383
  int dir = tid >> 13;
  int b   = (tid >> 11) & 3;
  int dn  = tid & 2047;
  const size_t stride = (size_t)BB*2048;
  size_t idx0 = (((size_t)dir*CH)*BB + b)*2048 + dn;

  const int U = 8;
  float pp[U], hh[U];
  #pragma unroll
  for (int u = 0; u < U; u++){
    pp[u] = P[idx0 + u*stride];
    hh[u] = Hout[idx0 + u*stride];
  }
  float h = 0.f;
  for (int c0 = 0; c0 < CH; c0 += U){
    float np[U], nh[U];
    if (c0 + U < CH){
      #pragma unroll
      for (int u = 0; u < U; u++){
        np[u] = P[idx0 + (size_t)(c0+U+u)*stride];
        nh[u] = Hout[idx0 + (size_t)(c0+U+u)*stride];
      }
    }
    #pragma unroll
    for (int u = 0; u < U; u++){
      Hin[idx0 + (size_t)(c0+u)*stride] = h;
      h = fmaf(pp[u], h, hh[u]);
    }
    if (c0 + U < CH){
      #pragma unroll
      for (int u = 0; u < U; u++){ pp[u] = np[u]; hh[u] = nh[u]; }
    }
  }
}

// Phase 3: read packed (xc,de), seeded scan, emit y (bf16). Same FAST path.
__global__ __launch_bounds__(256) void scan_p3(
    const unsigned int* __restrict__ xde,
    const float* __restrict__ xd,
    const float* __restrict__ Alogf, const float* __restrict__ Alogb,
    const float* __restrict__ Dfp, const float* __restrict__ Dbp,
    const float* Hin,
    unsigned short* __restrict__ yf, unsigned short* __restrict__ yb)
{
  int chunk = blockIdx.x, b = blockIdx.y, dir = blockIdx.z;
  const float* Alog = dir ? Alogb : Alogf;
  int d = threadIdx.x;
  int base = chunk*CLEN;

  __shared__ float sBC[CLEN*16];   // 2 KB: B (0..7) and C (8..15) per step
  {
    #pragma unroll
    for (int e = threadIdx.x; e < CLEN*16; e += 256){
      int lt = e >> 4, col = e & 15;
      int pos = base + lt;
      int row = dir ? (LL-1-pos) : pos;
      sBC[e] = xd[((size_t)b*LL + row)*64 + dir*32 + 16 + col];
    }
  }
  __syncthreads();

  float A[NST];
  bool fast = true;
  #pragma unroll
  for (int n = 0; n < NST; n++){
    A[n] = -__expf(Alog[d*NST + n]);
    fast = fast && (fabsf(A[n] + (float)(n+1)) < 1e-3f);
  }
  float Dd = (dir ? Dbp : Dfp)[d];

  float h[NST];
  {
    size_t ib = ((((size_t)dir*CH + chunk)*BB + b)*DD + d)*NST;
    float4 a0 = *(const float4*)&Hin[ib];
    float4 a1 = *(const float4*)&Hin[ib+4];
    h[0]=a0.x; h[1]=a0.y; h[2]=a0.z; h[3]=a0.w;
    h[4]=a1.x; h[5]=a1.y; h[6]=a1.z; h[7]=a1.w;
  }

  const unsigned int* xdep = xde + ((size_t)(dir*BB + b)*LL + base)*DD + d;
  unsigned short* yp = (dir ? yb : yf) + ((size_t)b*LL + base)*DD + d;

  const int U = 8;
  unsigned int pk[U];
  #pragma unroll
  for (int u = 0; u < U; u++) pk[u] = xdep[(size_t)u*DD];

  for (int t0 = 0; t0 < CLEN; t0 += U){
    unsigned int nk[U];
    if (t0 + U < CLEN){
      #pragma unroll
      for (int u = 0; u < U; u++) nk[u] = xdep[(size_t)(t0+U+u)*DD];
    }
    if (fast){
      #pragma unroll
      for (int u = 0; u < U; u++){
        int t = t0 + u;
        float xc = bf2f((unsigned short)(pk[u] & 0xffffu));
        float de = bf2f((unsigned short)(pk[u] >> 16));
        float dux = de * xc;
        const float* Bv = &sBC[t*16];
        const float* Cv = &sBC[t*16 + 8];
        float acc = xc * Dd;
        float e1 = __expf(-de);
        float dA = e1;
        h[0] = fmaf(dA, h[0], dux*Bv[0]); acc = fmaf(h[0], Cv[0], acc); dA *= e1;
        h[1] = fmaf(dA, h[1], dux*Bv[1]); acc = fmaf(h[1], Cv[1], acc); dA *= e1;
        h[2] = fmaf(dA, h[2], dux*Bv[2]); acc = fmaf(h[2], Cv[2], acc); dA *= e1;
        h[3] = fmaf(dA, h[3], dux*Bv[3]); acc = fmaf(h[3], Cv[3], acc); dA *= e1;
        h[4] = fmaf(dA, h[4], dux*Bv[4]); acc = fmaf(h[4], Cv[4], acc); dA *= e1;
        h[5] = fmaf(dA, h[5], dux*Bv[5]); acc = fmaf(h[5], Cv[5], acc); dA *= e1;
        h[6] = fmaf(dA, h[6], dux*Bv[6]); acc = fmaf(h[6], Cv[6], acc); dA *= e1;
        h[7] = fmaf(dA, h[7], dux*Bv[7]); acc = fmaf(h[7], Cv[7], acc);
        yp[(size_t)t*DD] = f2bf(acc);
      }
    } else {
      #pragma unroll
      for (int u = 0; u < U; u++){
        int t = t0 + u;
        float xc = bf2f((unsigned short)(pk[u] & 0xffffu));
        float de = bf2f((unsigned short)(pk[u] >> 16));
        float dux = de * xc;
        const float* Bv = &sBC[t*16];
        const float* Cv = &sBC[t*16 + 8];
        float acc = xc * Dd;
        #pragma unroll
        for (int n = 0; n < NST; n++){
          h[n] = fmaf(__expf(de*A[n]), h[n], dux*Bv[n]);
          acc = fmaf(h[n], Cv[n], acc);
        }
        yp[(size_t)t*DD] = f2bf(acc);
      }
    }
    if (t0 + U < CLEN){
      #pragma unroll
      for (int u = 0; u < U; u++) pk[u] = nk[u];
    }
  }
}

// ---------------- Combine: y=(yf+flip(yb))/2 -> rmsnorm -> *silu(z) -> bf16 ------
__global__ __launch_bounds__(64) void combine_kernel(
    const unsigned short* __restrict__ yf, const unsigned short* __restrict__ yb,
    const unsigned short* __restrict__ xz, const float* __restrict__ wn,
    unsigned short* __restrict__ outb)
{
  size_t tok = blockIdx.x;
  int b = (int)(tok / LL), t = (int)(tok % LL);
  int lane = threadIdx.x;
  ushort4 au = ((const ushort4*)(yf + tok*DD))[lane];
  ushort4 cu = ((const ushort4*)(yb + ((size_t)b*LL + (LL-1-t))*DD))[lane];
  float4 v;
  v.x=(bf2f(au.x)+bf2f(cu.x))*0.5f; v.y=(bf2f(au.y)+bf2f(cu.y))*0.5f;
  v.z=(bf2f(au.z)+bf2f(cu.z))*0.5f; v.w=(bf2f(au.w)+bf2f(cu.w))*0.5f;
  float s = v.x*v.x + v.y*v.y + v.z*v.z + v.w*v.w;
  #pragma unroll
  for (int m = 1; m < 64; m <<= 1) s += __shfl_xor(s, m, 64);
  float scale = 1.f / (sqrtf(s)*(1.f/16.f) + 1e-6f);
  float4 wv = ((const float4*)wn)[lane];
  ushort4 zv = *(const ushort4*)&xz[tok*XZS + 256 + lane*4];
  ushort4 r;
  r.x = f2bf(v.x*scale*wv.x*siluf(bf2f(zv.x)));
  r.y = f2bf(v.y*scale*wv.y*siluf(bf2f(zv.y)));
  r.z = f2bf(v.z*scale*wv.z*siluf(bf2f(zv.z)));
  r.w = f2bf(v.w*scale*wv.w*siluf(bf2f(zv.w)));
  ((ushort4*)(outb + tok*DD))[lane] = r;
}

// ---------------- FF depthwise conv k=3 pad(1,1) + SiLU -> bf16 ------------------
__global__ __launch_bounds__(256) void dwconv3_kernel(
    const float* __restrict__ m, const float* __restrict__ w,
    const float* __restrict__ bi, unsigned short* __restrict__ o)
{
  size_t gid = (size_t)blockIdx.x*256 + threadIdx.x;  // over BL*HID
  int c = (int)(gid % HID);
  int tok = (int)(gid / HID);
  int b = tok / LL, t = tok % LL;
  float acc = bi[c];
  #pragma unroll
  for (int k = 0; k < 3; k++){
    int tt = t - 1 + k;
    if (tt >= 0 && tt < LL)
      acc = fmaf(w[c*3 + k], m[((size_t)b*LL + tt)*HID + c], acc);
  }
  o[gid] = f2bf(siluf(acc));
}

extern "C" void kernel_launch(void* const* d_in, const int* in_sizes, int n_in,
                              void* d_out, int out_size, void* d_ws, size_t ws_size,
                              hipStream_t stream)
{
  const float* x0        = (const float*)d_in[0];
  const float* x1        = (const float*)d_in[1];
  const float* w_norm0   = (const float*)d_in[2];
  const float* w_norm1   = (const float*)d_in[3];
  const float* in_proj_w = (const float*)d_in[4];
  const float* conv_w_f  = (const float*)d_in[5];
  const float* conv_b_f  = (const float*)d_in[6];
  const float* xproj_w_f = (const float*)d_in[7];
  const float* dtproj_w_f= (const float*)d_in[8];
  const float* dtproj_b_f= (const float*)d_in[9];
  const float* A_log_f   = (const float*)d_in[10];
  const float* D_f       = (const float*)d_in[11];
  const float* conv_w_bw = (const float*)d_in[12];
  const float* conv_b_bw = (const float*)d_in[13];
  const float* xproj_w_bw= (const float*)d_in[14];
  const float* dtproj_w_bw=(const float*)d_in[15];
  const float* dtproj_b_bw=(const float*)d_in[16];
  const float* A_log_bw  = (const float*)d_in[17];
  const float* D_bw      = (const float*)d_in[18];
  const float* norm_y_w  = (const float*)d_in[19];
  const float* out_proj_w= (const float*)d_in[20];
  const float* fc1_w     = (const float*)d_in[21];
  const float* dw_w      = (const float*)d_in[22];
  const float* dw_b      = (const float*)d_in[23];
  const float* fc2_w     = (const float*)d_in[24];
  float* out = (float*)d_out;
  float* ws  = (float*)d_ws;

  // region map (floats, BLD each), lifetime-reused
  float* r0 = ws + 0*BLD;   // h0b (bf16) -> yfb (bf16)
  float* r1 = ws + 1*BLD;   // h1b (bf16) -> ybb (bf16)
  float* r2 = ws + 2*BLD;   // xz_b (bf16, BL x 512 = full region)
  float* r3 = ws + 3*BLD;   // xd (fp32 BLx64, 4MB) ; ycomb_b (bf16, after p3)
  float* r4 = ws + 4*BLD;   // xde (uint32, spans r4+r5) -> m1 (fp32)
  float* r5 = ws + 5*BLD;   //                           -> m2b (bf16)
  float* r6 = ws + 6*BLD;   // wbuf1 (bf16 in_proj) -> P/Hout carries (Hin aliases P)
  float* r7 = ws + 7*BLD;   // wbuf2 (bf16 weights) + xb (bf16)

  unsigned short* h0b   = (unsigned short*)r0;
  unsigned short* h1b   = (unsigned short*)r1;
  unsigned short* xz_b  = (unsigned short*)r2;   // BL x XZS
  float*          xd    = r3;                    // BL x 64 fp32
  unsigned int*   xde   = (unsigned int*)r4;     // 2*BLD dwords = r4+r5
  unsigned short* wbuf1 = (unsigned short*)r6;   // 131072 (512x256)
  unsigned short* yfb   = (unsigned short*)r0;
  unsigned short* ybb   = (unsigned short*)r1;
  const size_t CARRY = (size_t)2*CH*BB*DD*NST;   // 2,097,152 floats (8 MB)
  float* Pbuf = r6;
  float* Hout = r6 + CARRY;
  float* Hin  = Pbuf;                            // aliased; p2 reads-then-writes
  unsigned short* ycomb_b = (unsigned short*)r3; // overwrites dead xd after p3
  unsigned short* wbuf2   = (unsigned short*)r7;
  unsigned short* wb_xp   = wbuf2;               // 16384  (64x256)
  unsigned short* wb_out  = wbuf2 + 16384;       // 65536
  unsigned short* wb_fc1  = wbuf2 + 81920;       // 32768
  unsigned short* wb_fc2  = wbuf2 + 114688;      // 32768
  unsigned short* xb      = wbuf2 + 147456;      // BLD bf16
  float*          m1      = r4;
  unsigned short* m2b     = (unsigned short*)r5;

  // 0. weight conversions
  cvt1_kernel<<<dim3(512), 256, 0, stream>>>(in_proj_w, wbuf1, 131072);
  cvt5_kernel<<<dim3(576), 256, 0, stream>>>(
      xproj_w_f, xproj_w_bw, out_proj_w, fc1_w, fc2_w, wbuf2);

  // 1. RMSNorm x0 -> h0b, x1 -> h1b (both bf16)
  rms_kernel<<<dim3(BL,2), 64, 0, stream>>>(x0, w_norm0, h0b, x1, w_norm1, h1b);

  // 2. xz = h0 @ in_proj.T -> xz_b (bf16, one N=512 dispatch)
  gemm_mfma<3><<<dim3(BL/64, 8), 256, 0, stream>>>(
      h0b, wbuf1, nullptr, nullptr, xz_b, BL, XZS, 256);

  // 3. merged xproj: xd[t][0..31]=fwd dt/B/C, [32..63]=bwd (natural t order)
  gemm_mfma<0><<<dim3(BL/64, 1), 256, 0, stream>>>(
      h1b, wb_xp, xd, nullptr, nullptr, BL, 64, 256);

  // 4. front: conv+silu+delta + local scan (per dir) -> xde, P, Hout
  front_kernel<<<dim3(CH, BB, 2), 256, 0, stream>>>(
      xz_b, xd, conv_w_f, conv_b_f, conv_w_bw, conv_b_bw,
      dtproj_w_f, dtproj_b_f, dtproj_w_bw, dtproj_b_bw,
      A_log_f, A_log_bw, xde, Pbuf, Hout);

  // 5-6. carry + seeded re-scan
  scan_p2<<<dim3(256), 64, 0, stream>>>(Pbuf, Hout, Hin);
  scan_p3<<<dim3(CH,BB,2), 256, 0, stream>>>(
      xde, xd, A_log_f, A_log_bw, D_f, D_bw, Hin, yfb, ybb);

  // 7. combine + rmsnorm + gate -> ycomb_b (r3; xd dead)
  combine_kernel<<<dim3(BL), 64, 0, stream>>>(yfb, ybb, xz_b, norm_y_w, ycomb_b);

  // 8. x = y @ out_proj.T + residual(x0) -> d_out (fp32) + xb (bf16)
  gemm_mfma<1><<<dim3(BL/64, 4), 256, 0, stream>>>(
      ycomb_b, wb_out, out, x0, xb, BL, 256, 256);

  // 9. m1 = x @ fc1.T (fp32; overwrites dead xde)
  gemm_mfma<0><<<dim3(BL/64, 2), 256, 0, stream>>>(
      xb, wb_fc1, m1, nullptr, nullptr, BL, 128, 256);

  // 10. m2 = silu(dwconv3(m1)) -> bf16
  dwconv3_kernel<<<dim3((BL*HID)/256), 256, 0, stream>>>(m1, dw_w, dw_b, m2b);

  // 11. out = x + m2 @ fc2.T
  gemm_mfma<2><<<dim3(BL/64, 4), 256, 0, stream>>>(
      m2b, wb_fc2, out, out, nullptr, BL, 256, 128);
}